// Round 9
// baseline (190.417 us; speedup 1.0000x reference)
//
#include <hip/hip_runtime.h>

// B=4, S=4096, d_model=256, d_k=d_v=64
#define B_    4
#define S_    4096
#define DM    256
#define DK    64
#define NROWS (B_ * S_)        // 16384
#define LOG2E 1.4426950408889634f
// log2(1 + 2^-9): folded into the QK MFMA C-operand so that v_perm truncation
// of P becomes round-half-up; scale alpha cancels in num/den.
#define PACK_BIAS 0.0028151295f
#define NJ 32                  // 32-key tiles per wave: 4096 / (4 waves * 32)
#define GRID_BLKS 512

typedef __attribute__((ext_vector_type(8))) short bfrag;   // 8 bf16 (4 VGPRs)
typedef __attribute__((ext_vector_type(4))) float ffrag;   // 4 f32 acc

__device__ __forceinline__ unsigned bf16_rne_hi(float x) {
    unsigned u = __float_as_uint(x);
    return u + 0x7fffu + ((u >> 16) & 1u);
}
__device__ __forceinline__ unsigned short f2bf(float x) {
    return (unsigned short)(bf16_rne_hi(x) >> 16);
}
__device__ __forceinline__ unsigned pack_bf16x2(float lo, float hi) {
    return (bf16_rne_hi(hi) & 0xffff0000u) | (bf16_rne_hi(lo) >> 16);
}
__device__ __forceinline__ float fast_exp2(float x) {
#if __has_builtin(__builtin_amdgcn_exp2f)
    return __builtin_amdgcn_exp2f(x);
#else
    float r;
    asm("v_exp_f32 %0, %1\n\ts_nop 1" : "=v"(r) : "v"(x));
    return r;
#endif
}
__device__ __forceinline__ unsigned trunc_pack_bf16x2(float lo, float hi) {
    return __builtin_amdgcn_perm(__float_as_uint(hi), __float_as_uint(lo),
                                 0x07060302u);
}

// ---------------------------------------------------------------------------
// Single persistent kernel, 512 blocks x 256 threads.
// Co-residency: 20.5 KB LDS (<=80KB for 2/CU), ~160 unified VGPR (3 blk/CU)
// -> capacity >= 768 blocks > 512 -> all blocks resident -> software grid
// barrier (device-scope atomics, m20) cannot deadlock.
//  Phase A: per block, one vT 32-key tile (transpose+pair-permute to bf16)
//           and 64 projection rows (x in register A-frags, w staged via LDS
//           in two 32-col chunks; q-scale folds (1/8)*log2e).
//  [grid barrier: release-fence + atomic count + spin + acquire-fence]
//  Phase B: attention. Block = 32 q-rows x all 4096 keys; wave w covers keys
//           [w*1024, +1024) in NJ=32 tiles. Batch-stripe swizzle (b = blk&3).
//           Ping-pong register prefetch, deferred PV, trunc-pack P via
//           PACK_BIAS, raw v_exp. Block-local reduce IS the full softmax:
//           epilogue writes out = num/den directly (no partials).
// ---------------------------------------------------------------------------
__global__ __launch_bounds__(256) void mega_kernel(
    const float* __restrict__ q, const float* __restrict__ k,
    const float* __restrict__ v, const float* __restrict__ wq,
    const float* __restrict__ wk, unsigned short* __restrict__ qpb,
    unsigned short* __restrict__ kpb, unsigned short* __restrict__ vT,
    unsigned* __restrict__ barrier_ctr, float* __restrict__ out)
{
    __shared__ __align__(16) char smem[20480];
    const int lane = threadIdx.x & 63, w = threadIdx.x >> 6;
    const int m = lane & 15, quad = lane >> 4;
    const int bp = blockIdx.x;              // 0..511

    //======================= Phase A1: vT tile =============================
    {
        float (*tile)[65] = (float(*)[65])smem;      // 32 x 65 f32 = 8320 B
        const int b = bp >> 7, tt = bp & 127;        // tile tt of batch b
        const float4* src = (const float4*)(v + ((size_t)b * S_ + tt * 32) * DK);
#pragma unroll
        for (int i = 0; i < 2; ++i) {
            const int idx4 = i * 256 + threadIdx.x;  // < 512
            const int row = idx4 >> 4, c4 = idx4 & 15;
            const float4 vv = src[idx4];
            tile[row][c4 * 4 + 0] = vv.x;
            tile[row][c4 * 4 + 1] = vv.y;
            tile[row][c4 * 4 + 2] = vv.z;
            tile[row][c4 * 4 + 3] = vv.w;
        }
        __syncthreads();
        unsigned* dst = (unsigned*)(vT + (size_t)bp * 2048);
#pragma unroll
        for (int i = 0; i < 4; ++i) {
            const int u = i * 256 + threadIdx.x;     // < 1024
            const int d = u >> 4, c = u & 15;        // pos 2c -> key c, 2c+1 -> key c+16
            dst[d * 16 + c] = pack_bf16x2(tile[c][d], tile[c + 16][d]);
        }
    }

    //======================= Phase A2: projection ==========================
    {
        const int half = bp >> 8, rblk = bp & 255;
        const float* x = half ? k : q;
        const float* wsrc = half ? wk : wq;
        unsigned short* o = half ? kpb : qpb;
        const float scale = half ? 1.0f : 0.125f * LOG2E;
        const int rows0 = rblk * 64;                 // 64 rows/block

        // x A-frags: wave w owns rows rows0 + w*16 + m
        bfrag xa[8];
        const float4* xrow = (const float4*)(x + (size_t)(rows0 + w * 16 + m) * DM);
#pragma unroll
        for (int kf = 0; kf < 8; ++kf) {
            const float4 a0 = xrow[kf * 8 + quad * 2];
            const float4 a1 = xrow[kf * 8 + quad * 2 + 1];
            union { bfrag v; unsigned u[4]; } pk;
            pk.u[0] = pack_bf16x2(a0.x, a0.y);
            pk.u[1] = pack_bf16x2(a0.z, a0.w);
            pk.u[2] = pack_bf16x2(a1.x, a1.y);
            pk.u[3] = pack_bf16x2(a1.z, a1.w);
            xa[kf] = pk.v;
        }

        unsigned short* wlds = (unsigned short*)smem;   // [32][264] bf16
#pragma unroll
        for (int c = 0; c < 2; ++c) {                   // output-col chunks
            __syncthreads();                            // smem reuse guard
            const float4* wsrc4 = (const float4*)(wsrc + c * 32 * DM);
#pragma unroll
            for (int i = 0; i < 8; ++i) {
                const int idx4 = i * 256 + threadIdx.x; // < 2048
                const int row = idx4 >> 6, c4 = idx4 & 63;
                const float4 wv = wsrc4[idx4];
                uint2 pk2;
                pk2.x = pack_bf16x2(wv.x, wv.y);
                pk2.y = pack_bf16x2(wv.z, wv.w);
                *(uint2*)&wlds[row * 264 + c4 * 4] = pk2;
            }
            __syncthreads();
            ffrag a0 = (ffrag)(0.0f), a1 = (ffrag)(0.0f);
#pragma unroll
            for (int kf = 0; kf < 8; ++kf) {
                const bfrag B0 = *(const bfrag*)&wlds[(m) * 264 + kf * 32 + quad * 8];
                const bfrag B1 = *(const bfrag*)&wlds[(16 + m) * 264 + kf * 32 + quad * 8];
                a0 = __builtin_amdgcn_mfma_f32_16x16x32_bf16(xa[kf], B0, a0, 0, 0, 0);
                a1 = __builtin_amdgcn_mfma_f32_16x16x32_bf16(xa[kf], B1, a1, 0, 0, 0);
            }
#pragma unroll
            for (int r = 0; r < 4; ++r) {
                o[(rows0 + w * 16 + quad * 4 + r) * DK + c * 32 + m] =
                    f2bf(fmaxf(a0[r], 0.0f) * scale);
                o[(rows0 + w * 16 + quad * 4 + r) * DK + c * 32 + 16 + m] =
                    f2bf(fmaxf(a1[r], 0.0f) * scale);
            }
        }
    }

    //=================== software grid barrier =============================
    __syncthreads();
    if (threadIdx.x == 0) {
        __threadfence();                         // release phase-A writes
        atomicAdd(barrier_ctr, 1u);
        while (atomicAdd(barrier_ctr, 0u) < (unsigned)GRID_BLKS)
            __builtin_amdgcn_s_sleep(8);
        __threadfence();                         // acquire
    }
    __syncthreads();

    //======================= Phase B: attention ============================
    unsigned short* Plds = (unsigned short*)smem;       // [4][32*40] = 10240 B
    float* red0 = (float*)smem;                          // epilogue [2][2560]
    float* red1 = (float*)smem + 2560;

    const int b   = bp & 3;                 // batch stripe
    const int qgw = bp >> 2;                // 0..127
    const int qbase = (b * 128 + qgw) * 32;
    const int kstart = w * 1024;            // NJ=32 tiles of 32 keys

    bfrag qa[2][2];
#pragma unroll
    for (int mt = 0; mt < 2; ++mt)
#pragma unroll
        for (int kf = 0; kf < 2; ++kf)
            qa[mt][kf] = *(const bfrag*)&qpb[(qbase + mt * 16 + m) * DK + kf * 32 + quad * 8];

    ffrag oacc[2][4];
    float dacc[2][4];
#pragma unroll
    for (int mt = 0; mt < 2; ++mt) {
#pragma unroll
        for (int dt = 0; dt < 4; ++dt) oacc[mt][dt] = (ffrag)(0.0f);
#pragma unroll
        for (int r = 0; r < 4; ++r) dacc[mt][r] = 0.0f;
    }

    const unsigned short* kptr = kpb + ((size_t)b * S_ + kstart + m) * DK + quad * 8;
    const unsigned short* vptr = vT + ((size_t)(b * 128 + (kstart >> 5)) * 64 + m) * 32 + quad * 8;
    unsigned short* Pw = Plds + w * 1280;

    const ffrag cbias = (ffrag)(PACK_BIAS);

    bfrag kbuf[2][2][2], vbuf[2][4];
#pragma unroll
    for (int kt = 0; kt < 2; ++kt)
#pragma unroll
        for (int kf = 0; kf < 2; ++kf)
            kbuf[0][kt][kf] = *(const bfrag*)(kptr + kt * 1024 + kf * 32);
#pragma unroll
    for (int dt = 0; dt < 4; ++dt)
        vbuf[0][dt] = *(const bfrag*)(vptr + dt * 512);

    const unsigned short* knext = kptr + 2048;
    const unsigned short* vnext = vptr + 2048;

    bfrag pa0, pa1;

#pragma unroll 2
    for (int jj = 0; jj < NJ; ++jj) {
        const int p = jj & 1;

        if (jj < NJ - 1) {
#pragma unroll
            for (int kt = 0; kt < 2; ++kt)
#pragma unroll
                for (int kf = 0; kf < 2; ++kf)
                    kbuf[p ^ 1][kt][kf] = *(const bfrag*)(knext + kt * 1024 + kf * 32);
        }

        if (jj > 0) {
#pragma unroll
            for (int dt = 0; dt < 4; ++dt) {
                oacc[0][dt] = __builtin_amdgcn_mfma_f32_16x16x32_bf16(pa0, vbuf[p ^ 1][dt], oacc[0][dt], 0, 0, 0);
                oacc[1][dt] = __builtin_amdgcn_mfma_f32_16x16x32_bf16(pa1, vbuf[p ^ 1][dt], oacc[1][dt], 0, 0, 0);
            }
        }

        if (jj < NJ - 1) {
#pragma unroll
            for (int dt = 0; dt < 4; ++dt)
                vbuf[p ^ 1][dt] = *(const bfrag*)(vnext + dt * 512);
        }
        knext += 2048;
        vnext += 2048;

        ffrag s[2][2];
#pragma unroll
        for (int mt = 0; mt < 2; ++mt)
#pragma unroll
            for (int kt = 0; kt < 2; ++kt) {
                ffrag t = __builtin_amdgcn_mfma_f32_16x16x32_bf16(qa[mt][0], kbuf[p][kt][0], cbias, 0, 0, 0);
                s[mt][kt] = __builtin_amdgcn_mfma_f32_16x16x32_bf16(qa[mt][1], kbuf[p][kt][1], t, 0, 0, 0);
            }

        const bool mask0 = (jj == 0) && (w == 0) && (m == 0);
#pragma unroll
        for (int mt = 0; mt < 2; ++mt)
#pragma unroll
            for (int r = 0; r < 4; ++r) {
                float e0 = fast_exp2(s[mt][0][r]);
                float e1 = fast_exp2(s[mt][1][r]);
                if (mask0) e0 = 0.0f;
                dacc[mt][r] += e0 + e1;
                *(unsigned*)&Pw[(mt * 16 + quad * 4 + r) * 40 + m * 2] =
                    trunc_pack_bf16x2(e0, e1);
            }

        pa0 = *(const bfrag*)&Pw[(m) * 40 + quad * 8];
        pa1 = *(const bfrag*)&Pw[(16 + m) * 40 + quad * 8];
    }
    // final PV (tile NJ-1 = 31, odd -> vbuf[1])
#pragma unroll
    for (int dt = 0; dt < 4; ++dt) {
        oacc[0][dt] = __builtin_amdgcn_mfma_f32_16x16x32_bf16(pa0, vbuf[1][dt], oacc[0][dt], 0, 0, 0);
        oacc[1][dt] = __builtin_amdgcn_mfma_f32_16x16x32_bf16(pa1, vbuf[1][dt], oacc[1][dt], 0, 0, 0);
    }

    // den: reduce over the 16 key-lanes within each quad group
#pragma unroll
    for (int mt = 0; mt < 2; ++mt)
#pragma unroll
        for (int r = 0; r < 4; ++r) {
            float d = dacc[mt][r];
            d += __shfl_xor(d, 1, 64);
            d += __shfl_xor(d, 2, 64);
            d += __shfl_xor(d, 4, 64);
            d += __shfl_xor(d, 8, 64);
            dacc[mt][r] = d;
        }

    // cross-wave tree reduce, then w0 writes out = num/den directly
    __syncthreads();
    float* red[2] = { red0, red1 };
    if (w >= 2) {
#pragma unroll
        for (int mt = 0; mt < 2; ++mt) {
#pragma unroll
            for (int dt = 0; dt < 4; ++dt)
#pragma unroll
                for (int r = 0; r < 4; ++r)
                    red[w - 2][((mt * 4 + dt) * 4 + r) * 64 + lane] = oacc[mt][dt][r];
#pragma unroll
            for (int r = 0; r < 4; ++r)
                red[w - 2][2048 + (mt * 4 + r) * 64 + lane] = dacc[mt][r];
        }
    }
    __syncthreads();
    if (w < 2) {
#pragma unroll
        for (int mt = 0; mt < 2; ++mt) {
#pragma unroll
            for (int dt = 0; dt < 4; ++dt)
#pragma unroll
                for (int r = 0; r < 4; ++r)
                    oacc[mt][dt][r] += red[w][((mt * 4 + dt) * 4 + r) * 64 + lane];
#pragma unroll
            for (int r = 0; r < 4; ++r)
                dacc[mt][r] += red[w][2048 + (mt * 4 + r) * 64 + lane];
        }
    }
    __syncthreads();
    if (w == 1) {
#pragma unroll
        for (int mt = 0; mt < 2; ++mt) {
#pragma unroll
            for (int dt = 0; dt < 4; ++dt)
#pragma unroll
                for (int r = 0; r < 4; ++r)
                    red0[((mt * 4 + dt) * 4 + r) * 64 + lane] = oacc[mt][dt][r];
#pragma unroll
            for (int r = 0; r < 4; ++r)
                red0[2048 + (mt * 4 + r) * 64 + lane] = dacc[mt][r];
        }
    }
    __syncthreads();
    if (w == 0) {
#pragma unroll
        for (int mt = 0; mt < 2; ++mt) {
            float inv[4];
#pragma unroll
            for (int r = 0; r < 4; ++r)
                inv[r] = 1.0f / (dacc[mt][r] + red0[2048 + (mt * 4 + r) * 64 + lane]);
#pragma unroll
            for (int dt = 0; dt < 4; ++dt)
#pragma unroll
                for (int r = 0; r < 4; ++r) {
                    const float nv = oacc[mt][dt][r] + red0[((mt * 4 + dt) * 4 + r) * 64 + lane];
                    out[(qbase + mt * 16 + quad * 4 + r) * DK + dt * 16 + m] = nv * inv[r];
                }
        }
    }
}

// ---------------------------------------------------------------------------
extern "C" void kernel_launch(void* const* d_in, const int* in_sizes, int n_in,
                              void* d_out, int out_size, void* d_ws, size_t ws_size,
                              hipStream_t stream)
{
    const float* q  = (const float*)d_in[0];
    const float* k  = (const float*)d_in[1];
    const float* v  = (const float*)d_in[2];
    const float* wq = (const float*)d_in[3];
    const float* wk = (const float*)d_in[4];
    float* out = (float*)d_out;

    // ws: qpb 2M | kpb 2M | vT 2M | barrier counter 64B
    char* p = (char*)d_ws;
    unsigned short* qpb = (unsigned short*)p;   p += (size_t)NROWS * DK * 2;
    unsigned short* kpb = (unsigned short*)p;   p += (size_t)NROWS * DK * 2;
    unsigned short* vT  = (unsigned short*)p;   p += (size_t)B_ * DK * S_ * 2;
    unsigned* barrier_ctr = (unsigned*)p;

    hipMemsetAsync(barrier_ctr, 0, 64, stream);   // ws is poisoned 0xAA each call
    mega_kernel<<<GRID_BLKS, 256, 0, stream>>>(q, k, v, wq, wk, qpb, kpb, vT,
                                               barrier_ctr, out);
}

// Round 10
// 137.023 us; speedup vs baseline: 1.3897x; 1.3897x over previous
//
#include <hip/hip_runtime.h>

// B=4, S=4096, d_model=256, d_k=d_v=64
#define B_    4
#define S_    4096
#define DM    256
#define DK    64
#define NROWS (B_ * S_)        // 16384
#define LOG2E 1.4426950408889634f
// log2(1 + 2^-9): folded into the QK MFMA C-operand so that truncation-pack
// of P becomes round-half-up; scale alpha cancels in num/den.
#define PACK_BIAS 0.0028151295f
#define NSPLIT 2               // key splits (gy); 2 partials
#define NJ     16              // 32-key tiles per wave (4096 / (NSPLIT*4*32))
#define NQG    512             // q-groups of 32 rows

typedef __attribute__((ext_vector_type(8)))  short bfrag;  // 8 bf16 (4 VGPRs)
typedef __attribute__((ext_vector_type(4)))  float ffrag;  // 4 f32
typedef __attribute__((ext_vector_type(16))) float cfrag;  // 16 f32 (32x32 C/D)

__device__ __forceinline__ unsigned bf16_rne_hi(float x) {
    unsigned u = __float_as_uint(x);
    return u + 0x7fffu + ((u >> 16) & 1u);
}
__device__ __forceinline__ unsigned short f2bf(float x) {
    return (unsigned short)(bf16_rne_hi(x) >> 16);
}
__device__ __forceinline__ unsigned pack_bf16x2(float lo, float hi) {
    return (bf16_rne_hi(hi) & 0xffff0000u) | (bf16_rne_hi(lo) >> 16);
}
__device__ __forceinline__ float fast_exp2(float x) {
#if __has_builtin(__builtin_amdgcn_exp2f)
    return __builtin_amdgcn_exp2f(x);
#else
    float r;
    asm("v_exp_f32 %0, %1\n\ts_nop 1" : "=v"(r) : "v"(x));
    return r;
#endif
}
// truncation-pack (1 VALU); inputs pre-scaled by (1+2^-9) via MFMA C bias.
__device__ __forceinline__ unsigned trunc_pack_bf16x2(float lo, float hi) {
    return __builtin_amdgcn_perm(__float_as_uint(hi), __float_as_uint(lo),
                                 0x07060302u);
}

// ---------------------------------------------------------------------------
// Fused prep + projection (1280 blocks):
//   blocks 0..255   : vT[b][t][d][pos], t = key/32. Key order within a tile is
//                     the PV k-permutation {0-3,8-11,4-7,12-15}(+16): position
//                     pair (2c,2c+1) holds keys (2C,2C+1) with
//                     C = (c&1)|((c&2)<<1)|((c&4)>>1)|(c&8). This makes the
//                     QK C-register order coincide with the PV B-frag order
//                     (zero cross-lane movement for P).
//   blocks 256..1279: qp/kp = bf16(relu(x . w^T) * scale) via MFMA, 32 rows
//                     per block; x AND w staged through LDS fully coalesced.
//                     q-scale folds (1/8)*log2(e).
// ---------------------------------------------------------------------------
__global__ __launch_bounds__(256) void fused_prep(
    const float* __restrict__ q, const float* __restrict__ k,
    const float* __restrict__ v, const float* __restrict__ wq,
    const float* __restrict__ wk, unsigned short* __restrict__ vT,
    unsigned short* __restrict__ qpb, unsigned short* __restrict__ kpb)
{
    __shared__ __align__(16) char smem[50688];
    const int blk  = blockIdx.x;
    const int lane = threadIdx.x & 63, w = threadIdx.x >> 6;

    if (blk < 256) {
        // ---- vT transpose + PV-permute (64 keys per block) ----
        float (*tile)[65] = (float(*)[65])smem;          // 64 x 65 f32
        const int b = blk >> 6, s0 = (blk & 63) * 64;
        const float4* src = (const float4*)(v + (size_t)(b * S_ + s0) * DK);
#pragma unroll
        for (int i = 0; i < 4; ++i) {
            const int idx4 = i * 256 + threadIdx.x;      // < 1024
            const int row = idx4 >> 4, c4 = idx4 & 15;
            const float4 vv = src[idx4];
            tile[row][c4 * 4 + 0] = vv.x;
            tile[row][c4 * 4 + 1] = vv.y;
            tile[row][c4 * 4 + 2] = vv.z;
            tile[row][c4 * 4 + 3] = vv.w;
        }
        __syncthreads();
        unsigned* dst = (unsigned*)(vT + (size_t)(b * 128 + (s0 >> 5)) * 64 * 32);
#pragma unroll
        for (int i = 0; i < 8; ++i) {
            const int u = i * 256 + threadIdx.x;         // < 2048
            const int t32 = u >> 10, rem = u & 1023;
            const int d = rem >> 4, c = rem & 15;
            const int C2 = (c & 1) | ((c & 2) << 1) | ((c & 4) >> 1) | (c & 8);
            dst[(t32 * 64 + d) * 16 + c] =
                pack_bf16x2(tile[t32 * 32 + 2 * C2][d],
                            tile[t32 * 32 + 2 * C2 + 1][d]);
        }
    } else {
        // ---- projection: 32 rows/block; wave w owns output cols w*16..+15 ----
        unsigned short* xlds = (unsigned short*)smem;            // [32][264]
        unsigned short* wlds = (unsigned short*)(smem + 16896);  // [64][264]
        const int pb = blk - 256;                        // 0..1023
        const int half = pb >> 9, rblk = pb & 511;
        const float* x;
        const float* wsrc;
        unsigned short* o;
        float scale;
        if (half == 0) { x = q; wsrc = wq; o = qpb; scale = 0.125f * LOG2E; }
        else           { x = k; wsrc = wk; o = kpb; scale = 1.0f; }

        const int rows0 = rblk * 32;
        const float4* xsrc = (const float4*)(x + (size_t)rows0 * DM);
#pragma unroll
        for (int i = 0; i < 8; ++i) {                    // x: 32x256 f32 -> bf16
            const int idx4 = i * 256 + threadIdx.x;      // < 2048
            const int row = idx4 >> 6, c4 = idx4 & 63;
            const float4 xv = xsrc[idx4];
            uint2 pk2;
            pk2.x = pack_bf16x2(xv.x, xv.y);
            pk2.y = pack_bf16x2(xv.z, xv.w);
            *(uint2*)&xlds[row * 264 + c4 * 4] = pk2;
        }
#pragma unroll
        for (int i = 0; i < 16; ++i) {                   // w: 64x256 f32 -> bf16
            const int idx4 = i * 256 + threadIdx.x;      // < 4096
            const int row = idx4 >> 6, c4 = idx4 & 63;
            const float4 wv = ((const float4*)wsrc)[idx4];
            uint2 pk2;
            pk2.x = pack_bf16x2(wv.x, wv.y);
            pk2.y = pack_bf16x2(wv.z, wv.w);
            *(uint2*)&wlds[row * 264 + c4 * 4] = pk2;
        }
        __syncthreads();

        const int m = lane & 15, quad = lane >> 4;

        ffrag acc[2];
        acc[0] = (ffrag)(0.0f);
        acc[1] = (ffrag)(0.0f);

#pragma unroll
        for (int kf = 0; kf < 8; ++kf) {
            const bfrag Bf = *(const bfrag*)&wlds[(w * 16 + m) * 264 + kf * 32 + quad * 8];
#pragma unroll
            for (int mt = 0; mt < 2; ++mt) {
                const bfrag A = *(const bfrag*)&xlds[(mt * 16 + m) * 264 + kf * 32 + quad * 8];
                acc[mt] = __builtin_amdgcn_mfma_f32_16x16x32_bf16(A, Bf, acc[mt], 0, 0, 0);
            }
        }
#pragma unroll
        for (int mt = 0; mt < 2; ++mt)
#pragma unroll
            for (int r = 0; r < 4; ++r)
                o[(rows0 + mt * 16 + quad * 4 + r) * DK + w * 16 + m] =
                    f2bf(fmaxf(acc[mt][r], 0.0f) * scale);
    }
}

// ---------------------------------------------------------------------------
// Attention on 32x32x16 MFMA — no LDS in the main loop:
//  - Sᵀ = K·Qᵀ: A=K (row=key=lane&31, k=d), B=Q (col=q=lane&31, k=d).
//    C-layout (m74/m101): col=q, row(key) = (r&3)+8*(r>>2)+4*(lane>>5).
//  - PV: A=Vᵀ (row=d=lane&31, k=key in the prep permutation), B=P: lane's
//    16 exp'd C-regs pack pairwise straight into the two k-chunk B-frags
//    (vT's key order makes reg order == B-frag k order for BOTH lane halves).
//  - den: one f32/lane (its 16 keys x its q); epilogue shfl_xor(32) completes.
//  - 1024 blocks; sid=blk&7 -> (b,gy) stripe, 1 stripe/XCD (512 KB in L2).
//  - ping-pong register prefetch of K/V one tile ahead, unroll 2.
// ---------------------------------------------------------------------------
__global__ __launch_bounds__(256) void attn_mfma(
    const unsigned short* __restrict__ qp, const unsigned short* __restrict__ kp,
    const unsigned short* __restrict__ vT, float* __restrict__ num_part,
    float* __restrict__ den_part)
{
    __shared__ float red[2][2112];   // per source wave: 2048 oacc + 64 den

    const int lane = threadIdx.x & 63, w = threadIdx.x >> 6;
    const int l31 = lane & 31, g = lane >> 5;
    const int sid = blockIdx.x & 7;           // 1 stripe per XCD
    const int b   = sid >> 1, gy = sid & 1;
    const int qg  = blockIdx.x >> 3;          // 0..127 (within batch)
    const int qgg = b * 128 + qg;             // 0..511 global q-group
    const int qbase = qgg * 32;
    const int kstart = (gy * 4 + w) * 512;    // NJ=16 tiles of 32 keys

    // Q B-frags: col=q=l31, k=d
    bfrag qa[4];
#pragma unroll
    for (int s = 0; s < 4; ++s)
        qa[s] = *(const bfrag*)&qp[(qbase + l31) * DK + s * 16 + g * 8];

    cfrag oacc[2];                 // O^T halves: rows d(+32h), cols q
    oacc[0] = (cfrag)(0.0f);
    oacc[1] = (cfrag)(0.0f);
    float dacc = 0.0f;

    const unsigned short* kptr = kp + ((size_t)b * S_ + kstart + l31) * DK + g * 8;
    const unsigned short* vptr = vT + ((size_t)(b * 128 + (kstart >> 5)) * 64 + l31) * 32 + g * 8;

    cfrag cbias;
#pragma unroll
    for (int r = 0; r < 16; ++r) cbias[r] = PACK_BIAS;

    // preload tile 0 into slot 0
    bfrag kbuf[2][4], vbuf[2][2][2];
#pragma unroll
    for (int s = 0; s < 4; ++s)
        kbuf[0][s] = *(const bfrag*)(kptr + s * 16);
#pragma unroll
    for (int h = 0; h < 2; ++h)
#pragma unroll
        for (int kc = 0; kc < 2; ++kc)
            vbuf[0][h][kc] = *(const bfrag*)(vptr + h * 1024 + kc * 16);

    const unsigned short* knext = kptr + 2048;
    const unsigned short* vnext = vptr + 2048;

#pragma unroll 2
    for (int jj = 0; jj < NJ; ++jj) {
        const int p = jj & 1;

        // prefetch tile jj+1
        if (jj < NJ - 1) {
#pragma unroll
            for (int s = 0; s < 4; ++s)
                kbuf[p ^ 1][s] = *(const bfrag*)(knext + s * 16);
#pragma unroll
            for (int h = 0; h < 2; ++h)
#pragma unroll
                for (int kc = 0; kc < 2; ++kc)
                    vbuf[p ^ 1][h][kc] = *(const bfrag*)(vnext + h * 1024 + kc * 16);
            knext += 2048;
            vnext += 2048;
        }

        // S^T = K . Q^T (4 chained k-steps), C seeded with pack bias
        cfrag c = cbias;
#pragma unroll
        for (int s = 0; s < 4; ++s)
            c = __builtin_amdgcn_mfma_f32_32x32x16_bf16(kbuf[p][s], qa[s], c, 0, 0, 0);

        // exp (log2 domain), col-0 mask (key 0 <-> reg 0, lanes g==0)
        float e[16];
#pragma unroll
        for (int r = 0; r < 16; ++r) e[r] = fast_exp2(c[r]);
        if ((jj == 0) && (kstart == 0) && (g == 0)) e[0] = 0.0f;

        // den
        dacc += (((e[0] + e[1]) + (e[2] + e[3])) + ((e[4] + e[5]) + (e[6] + e[7])))
              + (((e[8] + e[9]) + (e[10] + e[11])) + ((e[12] + e[13]) + (e[14] + e[15])));

        // P B-frags: pairwise truncation-pack, reg order == k order (via vT perm)
        union { bfrag v; unsigned u[4]; } pf0, pf1;
#pragma unroll
        for (int d2 = 0; d2 < 4; ++d2) {
            pf0.u[d2] = trunc_pack_bf16x2(e[2 * d2], e[2 * d2 + 1]);
            pf1.u[d2] = trunc_pack_bf16x2(e[8 + 2 * d2], e[8 + 2 * d2 + 1]);
        }

        // O^T += V^T . P  (two d-halves x two key-chunks)
#pragma unroll
        for (int h = 0; h < 2; ++h) {
            oacc[h] = __builtin_amdgcn_mfma_f32_32x32x16_bf16(vbuf[p][h][0], pf0.v, oacc[h], 0, 0, 0);
            oacc[h] = __builtin_amdgcn_mfma_f32_32x32x16_bf16(vbuf[p][h][1], pf1.v, oacc[h], 0, 0, 0);
        }
    }

    // cross-wave tree reduce: {2,3} -> {0,1}, then 1 -> 0
    __syncthreads();
    if (w >= 2) {
#pragma unroll
        for (int h = 0; h < 2; ++h)
#pragma unroll
            for (int r = 0; r < 16; ++r)
                red[w - 2][(h * 16 + r) * 64 + lane] = oacc[h][r];
        red[w - 2][2048 + lane] = dacc;
    }
    __syncthreads();
    if (w < 2) {
#pragma unroll
        for (int h = 0; h < 2; ++h)
#pragma unroll
            for (int r = 0; r < 16; ++r)
                oacc[h][r] += red[w][(h * 16 + r) * 64 + lane];
        dacc += red[w][2048 + lane];
    }
    __syncthreads();
    if (w == 1) {
#pragma unroll
        for (int h = 0; h < 2; ++h)
#pragma unroll
            for (int r = 0; r < 16; ++r)
                red[0][(h * 16 + r) * 64 + lane] = oacc[h][r];
        red[0][2048 + lane] = dacc;
    }
    __syncthreads();
    if (w == 0) {
#pragma unroll
        for (int h = 0; h < 2; ++h)
#pragma unroll
            for (int r = 0; r < 16; ++r)
                oacc[h][r] += red[0][(h * 16 + r) * 64 + lane];
        dacc += red[0][2048 + lane];

        // num_part[gy][qgg][d(64)][q(32)] — coalesced 128B segments per reg
        float* np = num_part + ((size_t)gy * NQG + qgg) * 2048;
#pragma unroll
        for (int h = 0; h < 2; ++h)
#pragma unroll
            for (int r = 0; r < 16; ++r) {
                const int d = h * 32 + (r & 3) + 8 * (r >> 2) + 4 * g;
                np[d * 32 + l31] = oacc[h][r];
            }
        // den: combine the two lane halves (complementary key sets per q)
        const float dtot = dacc + __shfl_xor(dacc, 32, 64);
        if (g == 0)
            den_part[gy * NROWS + qbase + l31] = dtot;
    }
}

// ---------------------------------------------------------------------------
// Finalize: per q-group, sum the 2 partials, divide, transpose d-major ->
// q-major through LDS, write out coalesced.
// ---------------------------------------------------------------------------
__global__ __launch_bounds__(256) void finalize_kernel(
    const float* __restrict__ num_part, const float* __restrict__ den_part,
    float* __restrict__ out)
{
    __shared__ float trans[64][33];
    __shared__ float invd[32];
    const int qg = blockIdx.x;           // 0..511
    const int t  = threadIdx.x;

    if (t < 32)
        invd[t] = 1.0f / (den_part[qg * 32 + t] + den_part[NROWS + qg * 32 + t]);
    __syncthreads();

    const float* np0 = num_part + (size_t)qg * 2048;
    const float* np1 = num_part + (size_t)NQG * 2048 + (size_t)qg * 2048;
#pragma unroll
    for (int i = 0; i < 8; ++i) {
        const int idx = i * 256 + t;     // < 2048
        const int d = idx >> 5, qq = idx & 31;
        trans[d][qq] = (np0[idx] + np1[idx]) * invd[qq];
    }
    __syncthreads();
    float* ob = out + (size_t)qg * 2048;
#pragma unroll
    for (int i = 0; i < 8; ++i) {
        const int j = i * 256 + t;       // < 2048 ; out[q*64+d]
        ob[j] = trans[j & 63][j >> 6];
    }
}

// ---------------------------------------------------------------------------
extern "C" void kernel_launch(void* const* d_in, const int* in_sizes, int n_in,
                              void* d_out, int out_size, void* d_ws, size_t ws_size,
                              hipStream_t stream)
{
    const float* q  = (const float*)d_in[0];
    const float* k  = (const float*)d_in[1];
    const float* v  = (const float*)d_in[2];
    const float* wq = (const float*)d_in[3];
    const float* wk = (const float*)d_in[4];
    float* out = (float*)d_out;

    // ws: qpb 2M | kpb 2M | vT 2M | num_part 8M | den_part 128K
    char* p = (char*)d_ws;
    unsigned short* qpb = (unsigned short*)p;   p += (size_t)NROWS * DK * 2;
    unsigned short* kpb = (unsigned short*)p;   p += (size_t)NROWS * DK * 2;
    unsigned short* vT  = (unsigned short*)p;   p += (size_t)B_ * DK * S_ * 2;
    float* num_part     = (float*)p;            p += (size_t)NSPLIT * NROWS * DK * 4;
    float* den_part     = (float*)p;

    fused_prep<<<1280, 256, 0, stream>>>(q, k, v, wq, wk, vT, qpb, kpb);
    attn_mfma<<<1024, 256, 0, stream>>>(qpb, kpb, vT, num_part, den_part);
    finalize_kernel<<<NQG, 256, 0, stream>>>(num_part, den_part, out);
}